// Round 1
// baseline (139.611 us; speedup 1.0000x reference)
//
#include <hip/hip_runtime.h>

// 3D bilateral filter, radius 2 (125 taps), input (2,1,128,128,128) f32.
// v15: z-pair coarsening (4x * 2z = 8 voxels/thread) with z-row reuse.
// VALU-bound (VALUBusy ~90%, HBM 7%): tap floor 12 cyc is irreducible
// (sub2 + fma2 + cvt4 + add2 + fma2; VOP3P f32 is half-rate -> packed is a
// wash). Remaining gap = non-tap overhead + LDS-read stalls, both per-voxel
// traffic. Rows dz in [z-2,z+3] feed BOTH z and z+1: 30 row-reads / 1000
// taps vs 50 / 1000 before (-40% LDS reads/voxel), staging 4800 floats per
// 2048 voxels (-34%/voxel), block count halved (2048 blocks).
// Tap order per voxel identical to v12/v14 -> bitwise-same accumulation.
// Live set ~50 VGPR vs lb(256,6) budget 85 -> no spill expected.
// Spill sentinel: WRITE_SIZE must stay 16384 KB; VGPR_Count < 85.
// Epilogue: v_rcp_f32 + muls instead of 8 full divides (e in [1,125]).
// Tile pre-scaled by sR; OOB sentinel -> -inf -> cvt saturates -> w=+0.

#define RADIUS 2
#define N 128
#define TX 16
#define TY 8
#define TZ 16                        // z-tile; each thread owns a z-pair
#define PITCH (TX + 2 * RADIUS)      // 20 floats per row (16B-aligned rows)
#define LYD (TY + 2 * RADIUS)        // 12
#define LZD (TZ + 2 * RADIUS)        // 20
#define LDS_SIZE (PITCH * LYD * LZD) // 4800 floats = 18.75 KB

#define LOG2E 1.4426950408889634f
#define BIG 1.0e18f
#define EXP2_SCALE 8388608.0f        // 2^23
#define EXP2_BIAS 1065353216.0f      // 127 * 2^23

__global__ __launch_bounds__(256, 6) void bilateral3d_kernel(
    const float* __restrict__ in, const float* __restrict__ p_sx,
    const float* __restrict__ p_sy, const float* __restrict__ p_sz,
    const float* __restrict__ p_cs, float* __restrict__ out) {
  __shared__ float s[LDS_SIZE];

  const int tid = threadIdx.x;
  const int x0 = blockIdx.x * TX;
  const int y0 = blockIdx.y * TY;
  const int zb = blockIdx.z;  // low 3 bits = z-tile, bit 3 = batch
  const int z0 = (zb & 7) * TZ;
  const int b = zb >> 3;

  const float sxv = p_sx[0], syv = p_sy[0], szv = p_sz[0], csv = p_cs[0];
  const float AX2 = EXP2_SCALE * LOG2E / (2.0f * sxv * sxv);
  const float AY2 = EXP2_SCALE * LOG2E / (2.0f * syv * syv);
  const float AZ2 = EXP2_SCALE * LOG2E / (2.0f * szv * szv);
  const float AX2_4 = 4.0f * AX2;
  const float sR = __builtin_sqrtf(EXP2_SCALE * LOG2E / (2.0f * csv * csv));

  const float* vol = in + (size_t)b * (N * N * N);

  // --- stage 20x12x20 halo tile, PRE-SCALED by sR (OOB -> sentinel) ---
  for (int i = tid; i < LDS_SIZE; i += 256) {
    int lx = i % PITCH;
    int t = i / PITCH;
    int ly = t % LYD;
    int lz = t / LYD;
    int gx = x0 + lx - RADIUS;
    int gy = y0 + ly - RADIUS;
    int gz = z0 + lz - RADIUS;
    float v = BIG;
    if ((unsigned)gx < N && (unsigned)gy < N && (unsigned)gz < N)
      v = vol[((size_t)gz * N + gy) * N + gx];
    s[i] = v * sR;
  }
  __syncthreads();

  // lane decode: ty fast (v12 remap; conflict-minimal within octets)
  const int ty = tid & 7;
  const int tx = (tid >> 3) & 3;  // x-group: voxels x0+4tx .. x0+4tx+3
  const int tz = tid >> 5;        // z-pair index 0..7 -> voxels z0+2tz, +1

  const int xw = 4 * tx;  // word offset within row of this thread's window

  // centers (scaled): words [xw+2 .. xw+5] of the two (dz=0,dy=0) rows
  const int cbaseA = ((2 * tz + RADIUS) * LYD + (ty + RADIUS)) * PITCH + xw;
  const int cbaseB = cbaseA + LYD * PITCH;
  const float4 CA0 = *(const float4*)&s[cbaseA];
  const float4 CA1 = *(const float4*)&s[cbaseA + 4];
  const float4 CB0 = *(const float4*)&s[cbaseB];
  const float4 CB1 = *(const float4*)&s[cbaseB + 4];
  const float a0 = CA0.z, a1 = CA0.w, a2 = CA1.x, a3 = CA1.y;
  const float c0v = CB0.z, c1v = CB0.w, c2v = CB1.x, c3v = CB1.y;

  float nA0 = 0, nA1 = 0, nA2 = 0, nA3 = 0;
  float eA0 = 0, eA1 = 0, eA2 = 0, eA3 = 0;
  float nB0 = 0, nB1 = 0, nB2 = 0, nB3 = 0;
  float eB0 = 0, eB1 = 0, eB2 = 0, eB3 = 0;

  // scalar Schraudolph tap: 5 insts / 12 cyc
#define TAP(XC, FV, CC, NN, DD)                          \
  {                                                      \
    float _t = (XC) - (FV);                              \
    float _f = fmaf(_t, -_t, (CC));                      \
    unsigned _q;                                         \
    asm("v_cvt_u32_f32 %0, %1" : "=v"(_q) : "v"(_f));    \
    float _w = __uint_as_float(_q);                      \
    DD += _w;                                            \
    NN = fmaf(_w, (FV), NN);                             \
  }

  // 20 taps of one (dz,dy) row against one 4-voxel center set.
  // Same dx order as v12: -2, -1, 0, +1, +2.
#define ROW20(C0, C1, C4, X0, X1, X2, X3, N0, N1, N2, N3, E0, E1, E2, E3) \
  TAP(X0, f0, C4, N0, E0) TAP(X1, f1, C4, N1, E1)                          \
  TAP(X2, f2, C4, N2, E2) TAP(X3, f3, C4, N3, E3)                          \
  TAP(X0, f1, C1, N0, E0) TAP(X1, f2, C1, N1, E1)                          \
  TAP(X2, f3, C1, N2, E2) TAP(X3, f4, C1, N3, E3)                          \
  TAP(X0, f2, C0, N0, E0) TAP(X1, f3, C0, N1, E1)                          \
  TAP(X2, f4, C0, N2, E2) TAP(X3, f5, C0, N3, E3)                          \
  TAP(X0, f3, C1, N0, E0) TAP(X1, f4, C1, N1, E1)                          \
  TAP(X2, f5, C1, N2, E2) TAP(X3, f6, C1, N3, E3)                          \
  TAP(X0, f4, C4, N0, E0) TAP(X1, f5, C4, N1, E1)                          \
  TAP(X2, f6, C4, N2, E2) TAP(X3, f7, C4, N3, E3)

  // 6 z-rows cover dz in [-2,+2] for BOTH voxels of the pair:
  //   voxel A (z0+2tz):   dz_A = dzw-2, active for dzw <= 4
  //   voxel B (z0+2tz+1): dz_B = dzw-3, active for dzw >= 1
#pragma unroll 1
  for (int dzw = 0; dzw < 6; ++dzw) {
    const float d2A = (float)((dzw - 2) * (dzw - 2));
    const float d2B = (float)((dzw - 3) * (dzw - 3));
    const float pz2A = AZ2 * d2A;
    const float pz2B = AZ2 * d2B;
    const int zrow = (2 * tz + dzw) * LYD;
    const bool doA = (dzw <= 4);
    const bool doB = (dzw >= 1);
#pragma unroll
    for (int dy = 0; dy < 5; ++dy) {
      const float py2 = AY2 * (float)((dy - 2) * (dy - 2));
      const int rb = (zrow + (ty + dy)) * PITCH + xw;
      const float4 A = *(const float4*)&s[rb];
      const float4 B = *(const float4*)&s[rb + 4];
      const float f0 = A.x, f1 = A.y, f2 = A.z, f3 = A.w;
      const float f4 = B.x, f5 = B.y, f6 = B.z, f7 = B.w;
      if (doA) {
        const float cc0 = EXP2_BIAS - (pz2A + py2);
        const float cm1 = cc0 - AX2;    // |dx| = 1
        const float cm4 = cc0 - AX2_4;  // |dx| = 2
        ROW20(cc0, cm1, cm4, a0, a1, a2, a3,
              nA0, nA1, nA2, nA3, eA0, eA1, eA2, eA3)
      }
      if (doB) {
        const float cc0 = EXP2_BIAS - (pz2B + py2);
        const float cm1 = cc0 - AX2;
        const float cm4 = cc0 - AX2_4;
        ROW20(cc0, cm1, cm4, c0v, c1v, c2v, c3v,
              nB0, nB1, nB2, nB3, eB0, eB1, eB2, eB3)
      }
    }
  }

  // values were pre-scaled by sR: out = num / (den * sR).
  // den in [1,125] (self-tap w=1) -> raw v_rcp (1 ulp) is safe.
  const float isR = 1.0f / sR;
  float4 rA, rB;
  rA.x = (nA0 * __builtin_amdgcn_rcpf(eA0)) * isR;
  rA.y = (nA1 * __builtin_amdgcn_rcpf(eA1)) * isR;
  rA.z = (nA2 * __builtin_amdgcn_rcpf(eA2)) * isR;
  rA.w = (nA3 * __builtin_amdgcn_rcpf(eA3)) * isR;
  rB.x = (nB0 * __builtin_amdgcn_rcpf(eB0)) * isR;
  rB.y = (nB1 * __builtin_amdgcn_rcpf(eB1)) * isR;
  rB.z = (nB2 * __builtin_amdgcn_rcpf(eB2)) * isR;
  rB.w = (nB3 * __builtin_amdgcn_rcpf(eB3)) * isR;

  const int gy = y0 + ty;
  const int gzA = z0 + 2 * tz;
  const size_t obase = (((size_t)b * N + gzA) * N + gy) * N + (x0 + xw);
  *(float4*)&out[obase] = rA;
  *(float4*)&out[obase + (size_t)N * N] = rB;
}

extern "C" void kernel_launch(void* const* d_in, const int* in_sizes, int n_in,
                              void* d_out, int out_size, void* d_ws, size_t ws_size,
                              hipStream_t stream) {
  const float* in = (const float*)d_in[0];
  const float* sx = (const float*)d_in[1];
  const float* sy = (const float*)d_in[2];
  const float* sz = (const float*)d_in[3];
  const float* cs = (const float*)d_in[4];
  float* out = (float*)d_out;

  dim3 grid(N / TX, N / TY, (N / TZ) * 2);  // 8 x 16 x 16 = 2048 blocks
  bilateral3d_kernel<<<grid, 256, 0, stream>>>(in, sx, sy, sz, cs, out);
}

// Round 2
// 136.478 us; speedup vs baseline: 1.0230x; 1.0230x over previous
//
#include <hip/hip_runtime.h>

// 3D bilateral filter, radius 2 (125 taps), input (2,1,128,128,128) f32.
// v16 = v14 tap loop bitwise (4 voxels/thread, 16x8x8 tile) + two fixes:
//  1) staging rewrite: column-mapped (tid<240 -> one (lx,ly) column, decode
//     once), fully unrolled lz walk with CLAMPED addresses + post-select so
//     all 12 global loads are in flight at once. v14's rolled loop was
//     load->waitcnt->ds_write serialized (~12 latency exposures behind the
//     block barrier); v15 grew that to 19 and VALUBusy fell 89->83.
//  2) rcp epilogue instead of 8 full f32 divides (~200 cyc/thread, verified
//     numerically safe in v15: absmax unchanged at 0.03125).
// Lesson from v15 (halved LDS reads+conflicts, zero gain): LDS pipe is NOT
// the limiter (~31% busy). Limiter = tap VALU floor (12 cyc/tap: sub2 fma2
// cvt4 add2 fma2) + staging latency + epilogue. Do not re-try coarsening.
// Spill sentinels: WRITE_SIZE must stay 16384 KB; VGPR_Count < 85.
// Tile pre-scaled by sR; OOB sentinel -> -inf -> cvt saturates -> w=+0.

#define RADIUS 2
#define N 128
#define TX 16
#define TY 8
#define TZ 8
#define PITCH (TX + 2 * RADIUS)      // 20 floats per row (16B-aligned rows)
#define LYD (TY + 2 * RADIUS)        // 12
#define LZD (TZ + 2 * RADIUS)        // 12
#define LDS_SIZE (PITCH * LYD * LZD) // 2880 floats = 11.25 KB

#define LOG2E 1.4426950408889634f
#define BIG 1.0e18f
#define EXP2_SCALE 8388608.0f        // 2^23
#define EXP2_BIAS 1065353216.0f      // 127 * 2^23

__global__ __launch_bounds__(256, 6) void bilateral3d_kernel(
    const float* __restrict__ in, const float* __restrict__ p_sx,
    const float* __restrict__ p_sy, const float* __restrict__ p_sz,
    const float* __restrict__ p_cs, float* __restrict__ out) {
  __shared__ float s[LDS_SIZE];

  const int tid = threadIdx.x;
  const int x0 = blockIdx.x * TX;
  const int y0 = blockIdx.y * TY;
  const int zb = blockIdx.z;  // low 4 bits = z-tile, bit 4 = batch
  const int z0 = (zb & 15) * TZ;
  const int b = zb >> 4;

  const float sxv = p_sx[0], syv = p_sy[0], szv = p_sz[0], csv = p_cs[0];
  const float AX2 = EXP2_SCALE * LOG2E / (2.0f * sxv * sxv);
  const float AY2 = EXP2_SCALE * LOG2E / (2.0f * syv * syv);
  const float AZ2 = EXP2_SCALE * LOG2E / (2.0f * szv * szv);
  const float AX2_4 = 4.0f * AX2;
  const float sR = __builtin_sqrtf(EXP2_SCALE * LOG2E / (2.0f * csv * csv));

  const float* vol = in + (size_t)b * (N * N * N);

  // --- stage 20x12x12 halo tile, PRE-SCALED by sR (OOB -> sentinel) ---
  // Column mapping: thread (tid<240) owns column (lx,ly), walks 12 lz.
  // Addresses clamped to 0 so every load is issuable immediately; OOB
  // result replaced by sentinel afterwards. All 12 loads independent ->
  // one latency exposure instead of twelve.
  if (tid < 240) {
    const int lx = tid % PITCH;
    const int ly = tid / PITCH;
    const int gx = x0 + lx - RADIUS;
    const int gy = y0 + ly - RADIUS;
    const bool xyok = ((unsigned)gx < N) && ((unsigned)gy < N);
    const size_t xyoff = xyok ? ((size_t)gy * N + gx) : 0;
    const int lbase = ly * PITCH + lx;  // == tid (word within z-slab)
#pragma unroll
    for (int lz = 0; lz < LZD; ++lz) {
      const int gz = z0 + lz - RADIUS;
      const bool ok = xyok && ((unsigned)gz < N);
      const size_t off = ok ? ((size_t)gz * (N * N) + xyoff) : 0;
      const float raw = vol[off];          // clamped: always in-bounds
      const float v = ok ? raw : BIG;
      s[lz * (LYD * PITCH) + lbase] = v * sR;
    }
  }
  __syncthreads();

  // lane decode: ty fast (v12 remap; conflict-minimal within octets)
  const int ty = tid & 7;
  const int tx = (tid >> 3) & 3;  // x-group: voxels x0+4tx .. x0+4tx+3
  const int tz = tid >> 5;

  const int xw = 4 * tx;  // word offset within row of this thread's tap window

  // centers (scaled): words [xw+2 .. xw+5] of the (dz=0,dy=0) row
  const int cbase = ((tz + RADIUS) * LYD + (ty + RADIUS)) * PITCH + xw;
  const float4 CA = *(const float4*)&s[cbase];
  const float4 CB = *(const float4*)&s[cbase + 4];
  const float xc0 = CA.z, xc1 = CA.w, xc2 = CB.x, xc3 = CB.y;

  float n0 = 0, n1 = 0, n2 = 0, n3 = 0;
  float e0 = 0, e1 = 0, e2 = 0, e3 = 0;  // denominators

  // scalar Schraudolph tap: 5 insts / 12 cyc
#define TAP(XC, FV, CC, NN, DD)                          \
  {                                                      \
    float _t = (XC) - (FV);                              \
    float _f = fmaf(_t, -_t, (CC));                      \
    unsigned _q;                                         \
    asm("v_cvt_u32_f32 %0, %1" : "=v"(_q) : "v"(_f));    \
    float _w = __uint_as_float(_q);                      \
    DD += _w;                                            \
    NN = fmaf(_w, (FV), NN);                             \
  }

#pragma unroll 1
  for (int dz = -RADIUS; dz <= RADIUS; ++dz) {
    const float pz2 = AZ2 * (float)(dz * dz);
    const int zrow = (tz + RADIUS + dz) * LYD;
#pragma unroll
    for (int dy = -RADIUS; dy <= RADIUS; ++dy) {
      const float cc0 = EXP2_BIAS - (pz2 + AY2 * (float)(dy * dy));
      const float cm1 = cc0 - AX2;    // |dx| = 1
      const float cm4 = cc0 - AX2_4;  // |dx| = 2
      const int rb = (zrow + (ty + RADIUS + dy)) * PITCH + xw;
      const float4 A = *(const float4*)&s[rb];
      const float4 B = *(const float4*)&s[rb + 4];
      const float f0 = A.x, f1 = A.y, f2 = A.z, f3 = A.w;
      const float f4 = B.x, f5 = B.y, f6 = B.z, f7 = B.w;

      // dx = -2
      TAP(xc0, f0, cm4, n0, e0)
      TAP(xc1, f1, cm4, n1, e1)
      TAP(xc2, f2, cm4, n2, e2)
      TAP(xc3, f3, cm4, n3, e3)
      // dx = -1
      TAP(xc0, f1, cm1, n0, e0)
      TAP(xc1, f2, cm1, n1, e1)
      TAP(xc2, f3, cm1, n2, e2)
      TAP(xc3, f4, cm1, n3, e3)
      // dx = 0
      TAP(xc0, f2, cc0, n0, e0)
      TAP(xc1, f3, cc0, n1, e1)
      TAP(xc2, f4, cc0, n2, e2)
      TAP(xc3, f5, cc0, n3, e3)
      // dx = +1
      TAP(xc0, f3, cm1, n0, e0)
      TAP(xc1, f4, cm1, n1, e1)
      TAP(xc2, f5, cm1, n2, e2)
      TAP(xc3, f6, cm1, n3, e3)
      // dx = +2
      TAP(xc0, f4, cm4, n0, e0)
      TAP(xc1, f5, cm4, n1, e1)
      TAP(xc2, f6, cm4, n2, e2)
      TAP(xc3, f7, cm4, n3, e3)
    }
  }

  // values were pre-scaled by sR: out = num / (den * sR).
  // den in [1,125] (self-tap w = 1 exactly) -> raw v_rcp (1 ulp) is safe;
  // verified in v15: absmax unchanged (0.03125).
  const float isR = 1.0f / sR;
  float4 r;
  r.x = (n0 * __builtin_amdgcn_rcpf(e0)) * isR;
  r.y = (n1 * __builtin_amdgcn_rcpf(e1)) * isR;
  r.z = (n2 * __builtin_amdgcn_rcpf(e2)) * isR;
  r.w = (n3 * __builtin_amdgcn_rcpf(e3)) * isR;

  const int gz = z0 + tz, gy = y0 + ty;
  *(float4*)&out[(((size_t)b * N + gz) * N + gy) * N + (x0 + xw)] = r;
}

extern "C" void kernel_launch(void* const* d_in, const int* in_sizes, int n_in,
                              void* d_out, int out_size, void* d_ws, size_t ws_size,
                              hipStream_t stream) {
  const float* in = (const float*)d_in[0];
  const float* sx = (const float*)d_in[1];
  const float* sy = (const float*)d_in[2];
  const float* sz = (const float*)d_in[3];
  const float* cs = (const float*)d_in[4];
  float* out = (float*)d_out;

  dim3 grid(N / TX, N / TY, (N / TZ) * 2);  // 8 x 16 x 32
  bilateral3d_kernel<<<grid, 256, 0, stream>>>(in, sx, sy, sz, cs, out);
}